// Round 5
// baseline (301.720 us; speedup 1.0000x reference)
//
#include <hip/hip_runtime.h>
#include <hip/hip_fp16.h>

#define N_NODES_C 100000
#define N_EDGES_C 1600000
#define IN_F 128
#define OUT_F 64

#define BIN_SHIFT 9
#define BIN_SZ    512                                  // nodes per bin
#define NBIN      ((N_NODES_C + BIN_SZ - 1) / BIN_SZ)  // 196
#define NCHUNK    256
#define CH        (N_EDGES_C / NCHUNK)                 // 6250 exactly

#define GEMM_BLOCKS ((N_NODES_C + 1023) / 1024)        // 98: 16 waves x 64 nodes each
#define SROW 72                                        // LDS epilogue row pitch (f16), 144B

typedef __attribute__((ext_vector_type(8))) _Float16 half8;
typedef __attribute__((ext_vector_type(4))) float    f32x4;

// ---------------- Fused: GEMM (MFMA) + hist ----------------
// Blocks [0, GEMM_BLOCKS): h[n][64] = fp16(x[n][128] @ W[64][128]^T + b).
//   16 waves/block; each wave owns 64 nodes (4 tiles of 16), so the W->f16
//   fragment build (64 VGPR) is amortized 4x. Epilogue transposes through a
//   padded LDS slab so global stores are 2x uint4 per lane (coalesced),
//   replacing 16 scattered 2B stores (the round-3 30us culprit).
// Blocks [GEMM_BLOCKS, GEMM_BLOCKS+NCHUNK): per-chunk LDS histogram (unchanged
//   semantics). Fusion overlaps the two independent subgraphs in one launch.
__global__ __launch_bounds__(1024) void fused_gemm_hist_kernel(
    const float* __restrict__ x, const float* __restrict__ W,
    const float* __restrict__ bias, _Float16* __restrict__ h, int n,
    const int* __restrict__ dst, int* __restrict__ hist) {
  __shared__ __align__(16) _Float16 sout[16 * 16 * SROW];  // 16 waves x 16 rows x 144B
  __shared__ int hh[NBIN];
  const int t = threadIdx.x;

  if (blockIdx.x >= GEMM_BLOCKS) {
    // ---------------- hist part ----------------
    const int c = blockIdx.x - GEMM_BLOCKS;
    for (int i = t; i < NBIN; i += 1024) hh[i] = 0;
    __syncthreads();
    const int e0 = c * CH;
    for (int i = t; i < CH; i += 1024)
      atomicAdd(&hh[dst[e0 + i] >> BIN_SHIFT], 1);
    __syncthreads();
    for (int i = t; i < NBIN; i += 1024)
      hist[i * NCHUNK + c] = hh[i];                    // bin-major layout
    return;
  }

  // ---------------- gemm part ----------------
  const int wid  = t >> 6;
  const int lane = t & 63;
  const int lr   = lane & 15;   // A-row / B-col / D-col
  const int lg   = lane >> 4;   // k-group (and D row-group)
  const int wbase = (blockIdx.x * 16 + wid) * 64;
  if (wbase >= n) return;

  // B fragments: bfrag[nc][kc], lane holds W[nc*16+lr][kc*32+lg*8 .. +7]
  half8 bfrag[4][4];
#pragma unroll
  for (int nc = 0; nc < 4; ++nc) {
    const float* wrow = W + (size_t)(nc * 16 + lr) * IN_F + lg * 8;
#pragma unroll
    for (int kc = 0; kc < 4; ++kc) {
      float4 a = ((const float4*)(wrow + kc * 32))[0];
      float4 b = ((const float4*)(wrow + kc * 32))[1];
      half8 f;
      f[0] = (_Float16)a.x; f[1] = (_Float16)a.y;
      f[2] = (_Float16)a.z; f[3] = (_Float16)a.w;
      f[4] = (_Float16)b.x; f[5] = (_Float16)b.y;
      f[6] = (_Float16)b.z; f[7] = (_Float16)b.w;
      bfrag[nc][kc] = f;
    }
  }

  float bv[4];
#pragma unroll
  for (int nc = 0; nc < 4; ++nc) bv[nc] = bias[nc * 16 + lr];

  _Float16* sw = sout + wid * 16 * SROW;   // per-wave slab; wave-coherent LDS

#pragma unroll
  for (int ti = 0; ti < 4; ++ti) {
    const int node0 = wbase + ti * 16;
    if (node0 >= n) break;

    int ra = node0 + lr;
    if (ra >= n) ra = n - 1;               // clamp: row m only affects D row m
    const float* xp = x + (size_t)ra * IN_F + lg * 8;

    f32x4 acc[4] = {{0.f, 0.f, 0.f, 0.f}, {0.f, 0.f, 0.f, 0.f},
                    {0.f, 0.f, 0.f, 0.f}, {0.f, 0.f, 0.f, 0.f}};
#pragma unroll
    for (int kc = 0; kc < 4; ++kc) {
      float4 a = ((const float4*)(xp + kc * 32))[0];
      float4 b = ((const float4*)(xp + kc * 32))[1];
      half8 af;
      af[0] = (_Float16)a.x; af[1] = (_Float16)a.y;
      af[2] = (_Float16)a.z; af[3] = (_Float16)a.w;
      af[4] = (_Float16)b.x; af[5] = (_Float16)b.y;
      af[6] = (_Float16)b.z; af[7] = (_Float16)b.w;
#pragma unroll
      for (int nc = 0; nc < 4; ++nc)
        acc[nc] = __builtin_amdgcn_mfma_f32_16x16x32_f16(af, bfrag[nc][kc], acc[nc], 0, 0, 0);
    }

    // epilogue: D row = lg*4+r (local), col = nc*16+lr -> LDS -> coalesced store
#pragma unroll
    for (int nc = 0; nc < 4; ++nc)
#pragma unroll
      for (int r = 0; r < 4; ++r)
        sw[(lg * 4 + r) * SROW + nc * 16 + lr] = (_Float16)(acc[nc][r] + bv[nc]);
    // intra-wave LDS dependency only: compiler inserts lgkmcnt wait; no barrier
#pragma unroll
    for (int it = 0; it < 2; ++it) {
      int rl = (lane >> 3) + it * 8;
      int node = node0 + rl;
      if (node < n)
        ((uint4*)(h + (size_t)node * OUT_F))[lane & 7] =
            ((const uint4*)(sw + rl * SROW))[lane & 7];
    }
  }
}

// ---------------- scan_all: bin totals -> exclusive bin bases -> soff ----------
// Replaces reduce + scan_partials + scan_final (3 launches -> 1; single block).
// soff[i*NCHUNK+c] = binStart[i] + sum_{c'<c} hist[i][c'].
__global__ __launch_bounds__(1024) void scan_all_kernel(
    const int* __restrict__ hist, int* __restrict__ soff,
    int* __restrict__ binStart) {
  __shared__ int s[256];
  const int t = threadIdx.x;
  int total = 0;
  if (t < NBIN) {
    const int* row = hist + (size_t)t * NCHUNK;
    for (int c = 0; c < NCHUNK; ++c) total += row[c];
  }
  if (t < 256) s[t] = (t < NBIN) ? total : 0;
  __syncthreads();
  for (int off = 1; off < 256; off <<= 1) {
    int u = 0;
    if (t < 256 && t >= off) u = s[t - off];
    __syncthreads();
    if (t < 256) s[t] += u;
    __syncthreads();
  }
  if (t < NBIN) {
    int base = s[t] - total;                 // exclusive over bins
    binStart[t] = base;
    const int* row = hist + (size_t)t * NCHUNK;
    int* so = soff + (size_t)t * NCHUNK;
    int run = base;
    for (int c = 0; c < NCHUNK; ++c) { so[c] = run; run += row[c]; }
  }
}

// Phase 2: re-read chunk, append records at LDS-cursor positions.
__global__ __launch_bounds__(1024) void binscatter_kernel(
    const int* __restrict__ src, const int* __restrict__ dst,
    const float* __restrict__ w, const int* __restrict__ soff,
    int* __restrict__ stage_d, int2* __restrict__ stage_sw) {
  __shared__ int lcur[NBIN];
  const int t = threadIdx.x;
  const int c = blockIdx.x;
  for (int i = t; i < NBIN; i += 1024) lcur[i] = soff[i * NCHUNK + c];
  __syncthreads();
  const int e0 = c * CH;
  for (int i = t; i < CH; i += 1024) {
    int e = e0 + i;
    int d = dst[e];
    int p = atomicAdd(&lcur[d >> BIN_SHIFT], 1);
    stage_d[p]  = d;
    stage_sw[p] = make_int2(src[e] * OUT_F, __float_as_int(w[e]));
  }
}

// Phase 3: one block per bin, 1024 threads. Scan phase restricted to t<BIN_SZ.
__global__ __launch_bounds__(1024) void place_kernel(
    const int* __restrict__ binStart, const int* __restrict__ stage_d,
    const int2* __restrict__ stage_sw, int* __restrict__ row_ptr,
    int2* __restrict__ edges, int n) {
  __shared__ int lcount[BIN_SZ];
  __shared__ int s[BIN_SZ];
  __shared__ int lcur[BIN_SZ];
  const int t = threadIdx.x;
  const int b = blockIdx.x;
  const int base = binStart[b];
  const int end  = (b == NBIN - 1) ? N_EDGES_C : binStart[b + 1];
  const int node0 = b << BIN_SHIFT;

  if (t < BIN_SZ) lcount[t] = 0;
  __syncthreads();
  for (int i = base + t; i < end; i += 1024)
    atomicAdd(&lcount[stage_d[i] - node0], 1);
  __syncthreads();

  int v = 0;
  if (t < BIN_SZ) { v = lcount[t]; s[t] = v; }
  __syncthreads();
  for (int off = 1; off < BIN_SZ; off <<= 1) {
    int u = (t < BIN_SZ && t >= off) ? s[t - off] : 0;
    __syncthreads();
    if (t < BIN_SZ) s[t] += u;
    __syncthreads();
  }
  if (t < BIN_SZ) {
    int ex = base + s[t] - v;     // exclusive CSR offset for node node0+t
    int node = node0 + t;
    if (node < n) row_ptr[node] = ex;
    lcur[t] = ex;
  }
  __syncthreads();

  for (int i = base + t; i < end; i += 1024) {
    int d = stage_d[i];
    int p = atomicAdd(&lcur[d - node0], 1);
    edges[p] = stage_sw[i];
  }
  if (b == NBIN - 1 && t == 0) row_ptr[n] = N_EDGES_C;
}

// ---------------- SpMM hop (fp16 rows) ----------------
// 8 lanes per node (lane fl owns features [8fl..8fl+7]), 8 nodes per wave,
// 4-deep edge unroll. e.x = src*64 (element offset); fp16 row = 128 B.
__device__ inline void fma8_h(float* acc, uint4 r, float w) {
  unsigned u[4] = {r.x, r.y, r.z, r.w};
#pragma unroll
  for (int q = 0; q < 4; ++q) {
    __half2 h2 = *reinterpret_cast<__half2*>(&u[q]);
    float2 f = __half22float2(h2);
    acc[2 * q + 0] += w * f.x;
    acc[2 * q + 1] += w * f.y;
  }
}

template <int OUT32>
__global__ __launch_bounds__(256) void spmm16_kernel(
    const int* __restrict__ row_ptr, const int2* __restrict__ edges,
    const __half* __restrict__ hin, void* __restrict__ hout, int n) {
  const int node = blockIdx.x * 32 + (threadIdx.x >> 3);
  const int fl   = threadIdx.x & 7;     // feature octet
  if (node >= n) return;
  const int beg = row_ptr[node];
  const int end = row_ptr[node + 1];

  float acc[8] = {0.f, 0.f, 0.f, 0.f, 0.f, 0.f, 0.f, 0.f};
  int j = beg;
  for (; j + 3 < end; j += 4) {
    int2 e0 = edges[j + 0];
    int2 e1 = edges[j + 1];
    int2 e2 = edges[j + 2];
    int2 e3 = edges[j + 3];
    uint4 r0 = ((const uint4*)(hin + e0.x))[fl];
    uint4 r1 = ((const uint4*)(hin + e1.x))[fl];
    uint4 r2 = ((const uint4*)(hin + e2.x))[fl];
    uint4 r3 = ((const uint4*)(hin + e3.x))[fl];
    fma8_h(acc, r0, __int_as_float(e0.y));
    fma8_h(acc, r1, __int_as_float(e1.y));
    fma8_h(acc, r2, __int_as_float(e2.y));
    fma8_h(acc, r3, __int_as_float(e3.y));
  }
  for (; j < end; ++j) {
    int2 e = edges[j];
    uint4 r = ((const uint4*)(hin + e.x))[fl];
    fma8_h(acc, r, __int_as_float(e.y));
  }

  if (OUT32) {
    float* op = (float*)hout + (size_t)node * OUT_F + 8 * fl;
    ((float4*)op)[0] = make_float4(acc[0], acc[1], acc[2], acc[3]);
    ((float4*)op)[1] = make_float4(acc[4], acc[5], acc[6], acc[7]);
  } else {
    union { __half2 h2[4]; uint4 u; } pk;
#pragma unroll
    for (int q = 0; q < 4; ++q)
      pk.h2[q] = __floats2half2_rn(acc[2 * q], acc[2 * q + 1]);
    ((uint4*)((char*)hout + (size_t)node * 128))[fl] = pk.u;
  }
}

extern "C" void kernel_launch(void* const* d_in, const int* in_sizes, int n_in,
                              void* d_out, int out_size, void* d_ws, size_t ws_size,
                              hipStream_t stream) {
  const float* x    = (const float*)d_in[0];
  const int*   ei   = (const int*)d_in[1];   // int32 (harness materializes ints as int32)
  const float* ew   = (const float*)d_in[2];
  const float* W    = (const float*)d_in[3];
  const float* bias = (const float*)d_in[4];
  float* out = (float*)d_out;

  const int N = N_NODES_C;
  const int E = N_EDGES_C;
  const int* src = ei;
  const int* dst = ei + E;
  const int NH = NBIN * NCHUNK;        // 50176 hist entries

  char* p = (char*)d_ws;
  auto carve = [&](size_t bytes) {
    void* r = (void*)p;
    p += (bytes + 255) & ~(size_t)255;
    return r;
  };
  __half* h16A     = (__half*)carve((size_t)N * OUT_F * 2);
  __half* h16B     = (__half*)carve((size_t)N * OUT_F * 2);
  int*   row_ptr   = (int*)  carve((size_t)(N + 1) * 4);
  int2*  edges     = (int2*) carve((size_t)E * 8);
  int*   hist      = (int*)  carve((size_t)NH * 4);
  int*   soff      = (int*)  carve((size_t)NH * 4);
  int*   binStart  = (int*)  carve((size_t)(NBIN + 1) * 4);

  // staging in d_out (free scratch until the final hop): sw 12.8MB + d 6.4MB
  int2* stage_sw = (int2*)d_out;
  int*  stage_d  = (int*)((char*)d_out + (size_t)E * 8);

  // 1. gemm (blocks 0..97) + hist (blocks 98..353) in one launch
  fused_gemm_hist_kernel<<<GEMM_BLOCKS + NCHUNK, 1024, 0, stream>>>(
      x, W, bias, (_Float16*)h16A, N, dst, hist);
  // 2. all scans in one single-block kernel
  scan_all_kernel<<<1, 1024, 0, stream>>>(hist, soff, binStart);
  // 3-4. two-phase binned counting sort (no global atomics)
  binscatter_kernel<<<NCHUNK, 1024, 0, stream>>>(src, dst, ew, soff, stage_d, stage_sw);
  place_kernel<<<NBIN, 1024, 0, stream>>>(binStart, stage_d, stage_sw,
                                          row_ptr, edges, N);
  // 5-7. three hops: fp16 -> fp16 -> fp16 -> fp32(out)
  spmm16_kernel<0><<<(N + 31) / 32, 256, 0, stream>>>(row_ptr, edges, h16A, h16B, N);
  spmm16_kernel<0><<<(N + 31) / 32, 256, 0, stream>>>(row_ptr, edges, h16B, h16A, N);
  spmm16_kernel<1><<<(N + 31) / 32, 256, 0, stream>>>(row_ptr, edges, h16A, out, N);
}

// Round 6
// 278.673 us; speedup vs baseline: 1.0827x; 1.0827x over previous
//
#include <hip/hip_runtime.h>
#include <hip/hip_fp16.h>

#define N_NODES_C 100000
#define N_EDGES_C 1600000
#define IN_F 128
#define OUT_F 64

#define BIN_SHIFT 9
#define BIN_SZ    512                                  // nodes per bin
#define NBIN      ((N_NODES_C + BIN_SZ - 1) / BIN_SZ)  // 196
#define NCHUNK    256
#define CH        (N_EDGES_C / NCHUNK)                 // 6250 exactly

#define SROW 72                                        // LDS epilogue row pitch (f16), 144B

typedef __attribute__((ext_vector_type(8))) _Float16 half8;
typedef __attribute__((ext_vector_type(4))) float    f32x4;

// ---------------- GEMM via MFMA: h[n][64] = fp16(x[n][128] @ W[64][128]^T + b) ----
// 256 threads = 4 waves/block; each wave owns 64 nodes (4 tiles of 16), so the
// W->f16 fragment build (64 VGPR) is amortized 4x. SEPARATE kernel with
// launch_bounds(256): round-5's 1024-thread fusion capped VGPR at 64 and
// spilled bfrag to scratch (47.7us, MfmaUtil 1.1%). Epilogue goes through a
// padded per-wave LDS slab so global stores are 2x uint4/lane (1KB/instr
// contiguous), replacing 16 scattered 2B stores (round-3's 30us culprit).
// Fragment maps (m89/m97-verified): A row=lane&15, k=(lane>>4)*8+i;
// B col=lane&15, same k map (common k-permutation cancels);
// D col=lane&15, row=(lane>>4)*4+reg.
__global__ __launch_bounds__(256) void gemm_mfma_kernel(
    const float* __restrict__ x, const float* __restrict__ W,
    const float* __restrict__ bias, _Float16* __restrict__ h, int n) {
  __shared__ __align__(16) _Float16 sout[4 * 16 * SROW];  // 4 waves x 16 rows x 144B
  const int t    = threadIdx.x;
  const int wid  = t >> 6;
  const int lane = t & 63;
  const int lr   = lane & 15;   // A-row / B-col / D-col
  const int lg   = lane >> 4;   // k-group (and D row-group)
  const int wbase = (blockIdx.x * 4 + wid) * 64;
  if (wbase >= n) return;

  // B fragments: bfrag[nc][kc], lane holds W[nc*16+lr][kc*32+lg*8 .. +7]
  half8 bfrag[4][4];
#pragma unroll
  for (int nc = 0; nc < 4; ++nc) {
    const float* wrow = W + (size_t)(nc * 16 + lr) * IN_F + lg * 8;
#pragma unroll
    for (int kc = 0; kc < 4; ++kc) {
      float4 a = ((const float4*)(wrow + kc * 32))[0];
      float4 b = ((const float4*)(wrow + kc * 32))[1];
      half8 f;
      f[0] = (_Float16)a.x; f[1] = (_Float16)a.y;
      f[2] = (_Float16)a.z; f[3] = (_Float16)a.w;
      f[4] = (_Float16)b.x; f[5] = (_Float16)b.y;
      f[6] = (_Float16)b.z; f[7] = (_Float16)b.w;
      bfrag[nc][kc] = f;
    }
  }

  float bv[4];
#pragma unroll
  for (int nc = 0; nc < 4; ++nc) bv[nc] = bias[nc * 16 + lr];

  _Float16* sw = sout + wid * 16 * SROW;   // per-wave slab; wave-coherent LDS

#pragma unroll
  for (int ti = 0; ti < 4; ++ti) {
    const int node0 = wbase + ti * 16;
    if (node0 >= n) break;

    int ra = node0 + lr;
    if (ra >= n) ra = n - 1;               // clamp: row m only affects D row m
    const float* xp = x + (size_t)ra * IN_F + lg * 8;

    f32x4 acc[4] = {{0.f, 0.f, 0.f, 0.f}, {0.f, 0.f, 0.f, 0.f},
                    {0.f, 0.f, 0.f, 0.f}, {0.f, 0.f, 0.f, 0.f}};
#pragma unroll
    for (int kc = 0; kc < 4; ++kc) {
      float4 a = ((const float4*)(xp + kc * 32))[0];
      float4 b = ((const float4*)(xp + kc * 32))[1];
      half8 af;
      af[0] = (_Float16)a.x; af[1] = (_Float16)a.y;
      af[2] = (_Float16)a.z; af[3] = (_Float16)a.w;
      af[4] = (_Float16)b.x; af[5] = (_Float16)b.y;
      af[6] = (_Float16)b.z; af[7] = (_Float16)b.w;
#pragma unroll
      for (int nc = 0; nc < 4; ++nc)
        acc[nc] = __builtin_amdgcn_mfma_f32_16x16x32_f16(af, bfrag[nc][kc], acc[nc], 0, 0, 0);
    }

    // epilogue: D row = lg*4+r (local), col = nc*16+lr -> LDS -> coalesced store
#pragma unroll
    for (int nc = 0; nc < 4; ++nc)
#pragma unroll
      for (int r = 0; r < 4; ++r)
        sw[(lg * 4 + r) * SROW + nc * 16 + lr] = (_Float16)(acc[nc][r] + bv[nc]);
    // intra-wave LDS dependency only: compiler inserts lgkmcnt wait; no barrier
#pragma unroll
    for (int it = 0; it < 2; ++it) {
      int rl = (lane >> 3) + it * 8;
      int node = node0 + rl;
      if (node < n)
        ((uint4*)(h + (size_t)node * OUT_F))[lane & 7] =
            ((const uint4*)(sw + rl * SROW))[lane & 7];
    }
  }
}

// ---------------- CSR build: LDS-binned counting sort ----------------
// Phase 1: per-chunk LDS histogram over 196 bins. 1024 threads (16 waves/CU
// hides the dependent load->LDS-atomic chain).
__global__ __launch_bounds__(1024) void hist_kernel(
    const int* __restrict__ dst, int* __restrict__ hist) {
  __shared__ int h[NBIN];
  const int t = threadIdx.x;
  for (int i = t; i < NBIN; i += 1024) h[i] = 0;
  __syncthreads();
  const int e0 = blockIdx.x * CH;
  for (int i = t; i < CH; i += 1024)
    atomicAdd(&h[dst[e0 + i] >> BIN_SHIFT], 1);
  __syncthreads();
  for (int i = t; i < NBIN; i += 1024)
    hist[i * NCHUNK + blockIdx.x] = h[i];      // bin-major layout
}

// ---------------- scan_all: wave-parallel, coalesced ----------------
// Replaces reduce + scan_partials + scan_final. Wave w handles bin rows
// w, w+16, ...; int4 loads (lane*16B, coalesced); shfl-based wave scan.
// Phase A: row totals. Phase B: wave 0 scans 196 totals -> binStart/binBase.
// Phase C: per-row 256-chunk exclusive scan + base -> soff.
__global__ __launch_bounds__(1024) void scan_all_kernel(
    const int* __restrict__ hist, int* __restrict__ soff,
    int* __restrict__ binStart) {
  __shared__ __align__(16) int binTot[256];
  __shared__ __align__(16) int binBase[256];
  const int t = threadIdx.x;
  const int w = t >> 6, lane = t & 63;

  for (int b = w; b < NBIN; b += 16) {
    int4 v = ((const int4*)(hist + (size_t)b * NCHUNK))[lane];
    int s = v.x + v.y + v.z + v.w;
#pragma unroll
    for (int off = 1; off < 64; off <<= 1) s += __shfl_xor(s, off);
    if (lane == 0) binTot[b] = s;
  }
  if (t >= NBIN && t < 256) binTot[t] = 0;
  __syncthreads();

  if (w == 0) {
    int4 v = ((const int4*)binTot)[lane];
    int s0 = v.x, s1 = s0 + v.y, s2 = s1 + v.z, s3 = s2 + v.w;
    int ls = s3;
#pragma unroll
    for (int off = 1; off < 64; off <<= 1) {
      int u = __shfl_up(ls, off);
      if (lane >= off) ls += u;
    }
    int ex = ls - s3;                        // exclusive over lanes
    int4 o;
    o.x = ex; o.y = ex + s0; o.z = ex + s1; o.w = ex + s2;
    ((int4*)binBase)[lane] = o;
  }
  __syncthreads();

  if (t < NBIN) binStart[t] = binBase[t];

  for (int b = w; b < NBIN; b += 16) {
    int base = binBase[b];
    int4 v = ((const int4*)(hist + (size_t)b * NCHUNK))[lane];
    int s0 = v.x, s1 = s0 + v.y, s2 = s1 + v.z, s3 = s2 + v.w;
    int ls = s3;
#pragma unroll
    for (int off = 1; off < 64; off <<= 1) {
      int u = __shfl_up(ls, off);
      if (lane >= off) ls += u;
    }
    int ex = base + ls - s3;
    int4 o;
    o.x = ex; o.y = ex + s0; o.z = ex + s1; o.w = ex + s2;
    ((int4*)(soff + (size_t)b * NCHUNK))[lane] = o;
  }
}

// Phase 2: re-read chunk, append records at LDS-cursor positions.
__global__ __launch_bounds__(1024) void binscatter_kernel(
    const int* __restrict__ src, const int* __restrict__ dst,
    const float* __restrict__ w, const int* __restrict__ soff,
    int* __restrict__ stage_d, int2* __restrict__ stage_sw) {
  __shared__ int lcur[NBIN];
  const int t = threadIdx.x;
  const int c = blockIdx.x;
  for (int i = t; i < NBIN; i += 1024) lcur[i] = soff[i * NCHUNK + c];
  __syncthreads();
  const int e0 = c * CH;
  for (int i = t; i < CH; i += 1024) {
    int e = e0 + i;
    int d = dst[e];
    int p = atomicAdd(&lcur[d >> BIN_SHIFT], 1);
    stage_d[p]  = d;
    stage_sw[p] = make_int2(src[e] * OUT_F, __float_as_int(w[e]));
  }
}

// Phase 3: one block per bin, 1024 threads. Scan phase restricted to t<BIN_SZ.
__global__ __launch_bounds__(1024) void place_kernel(
    const int* __restrict__ binStart, const int* __restrict__ stage_d,
    const int2* __restrict__ stage_sw, int* __restrict__ row_ptr,
    int2* __restrict__ edges, int n) {
  __shared__ int lcount[BIN_SZ];
  __shared__ int s[BIN_SZ];
  __shared__ int lcur[BIN_SZ];
  const int t = threadIdx.x;
  const int b = blockIdx.x;
  const int base = binStart[b];
  const int end  = (b == NBIN - 1) ? N_EDGES_C : binStart[b + 1];
  const int node0 = b << BIN_SHIFT;

  if (t < BIN_SZ) lcount[t] = 0;
  __syncthreads();
  for (int i = base + t; i < end; i += 1024)
    atomicAdd(&lcount[stage_d[i] - node0], 1);
  __syncthreads();

  int v = 0;
  if (t < BIN_SZ) { v = lcount[t]; s[t] = v; }
  __syncthreads();
  for (int off = 1; off < BIN_SZ; off <<= 1) {
    int u = (t < BIN_SZ && t >= off) ? s[t - off] : 0;
    __syncthreads();
    if (t < BIN_SZ) s[t] += u;
    __syncthreads();
  }
  if (t < BIN_SZ) {
    int ex = base + s[t] - v;     // exclusive CSR offset for node node0+t
    int node = node0 + t;
    if (node < n) row_ptr[node] = ex;
    lcur[t] = ex;
  }
  __syncthreads();

  for (int i = base + t; i < end; i += 1024) {
    int d = stage_d[i];
    int p = atomicAdd(&lcur[d - node0], 1);
    edges[p] = stage_sw[i];
  }
  if (b == NBIN - 1 && t == 0) row_ptr[n] = N_EDGES_C;
}

// ---------------- SpMM hop (fp16 rows) ----------------
// 8 lanes per node (lane fl owns features [8fl..8fl+7]), 8 nodes per wave,
// 4-deep edge unroll. e.x = src*64 (element offset); fp16 row = 128 B.
__device__ inline void fma8_h(float* acc, uint4 r, float w) {
  unsigned u[4] = {r.x, r.y, r.z, r.w};
#pragma unroll
  for (int q = 0; q < 4; ++q) {
    __half2 h2 = *reinterpret_cast<__half2*>(&u[q]);
    float2 f = __half22float2(h2);
    acc[2 * q + 0] += w * f.x;
    acc[2 * q + 1] += w * f.y;
  }
}

template <int OUT32>
__global__ __launch_bounds__(256) void spmm16_kernel(
    const int* __restrict__ row_ptr, const int2* __restrict__ edges,
    const __half* __restrict__ hin, void* __restrict__ hout, int n) {
  const int node = blockIdx.x * 32 + (threadIdx.x >> 3);
  const int fl   = threadIdx.x & 7;     // feature octet
  if (node >= n) return;
  const int beg = row_ptr[node];
  const int end = row_ptr[node + 1];

  float acc[8] = {0.f, 0.f, 0.f, 0.f, 0.f, 0.f, 0.f, 0.f};
  int j = beg;
  for (; j + 3 < end; j += 4) {
    int2 e0 = edges[j + 0];
    int2 e1 = edges[j + 1];
    int2 e2 = edges[j + 2];
    int2 e3 = edges[j + 3];
    uint4 r0 = ((const uint4*)(hin + e0.x))[fl];
    uint4 r1 = ((const uint4*)(hin + e1.x))[fl];
    uint4 r2 = ((const uint4*)(hin + e2.x))[fl];
    uint4 r3 = ((const uint4*)(hin + e3.x))[fl];
    fma8_h(acc, r0, __int_as_float(e0.y));
    fma8_h(acc, r1, __int_as_float(e1.y));
    fma8_h(acc, r2, __int_as_float(e2.y));
    fma8_h(acc, r3, __int_as_float(e3.y));
  }
  for (; j < end; ++j) {
    int2 e = edges[j];
    uint4 r = ((const uint4*)(hin + e.x))[fl];
    fma8_h(acc, r, __int_as_float(e.y));
  }

  if (OUT32) {
    float* op = (float*)hout + (size_t)node * OUT_F + 8 * fl;
    ((float4*)op)[0] = make_float4(acc[0], acc[1], acc[2], acc[3]);
    ((float4*)op)[1] = make_float4(acc[4], acc[5], acc[6], acc[7]);
  } else {
    union { __half2 h2[4]; uint4 u; } pk;
#pragma unroll
    for (int q = 0; q < 4; ++q)
      pk.h2[q] = __floats2half2_rn(acc[2 * q], acc[2 * q + 1]);
    ((uint4*)((char*)hout + (size_t)node * 128))[fl] = pk.u;
  }
}

extern "C" void kernel_launch(void* const* d_in, const int* in_sizes, int n_in,
                              void* d_out, int out_size, void* d_ws, size_t ws_size,
                              hipStream_t stream) {
  const float* x    = (const float*)d_in[0];
  const int*   ei   = (const int*)d_in[1];   // int32 (harness materializes ints as int32)
  const float* ew   = (const float*)d_in[2];
  const float* W    = (const float*)d_in[3];
  const float* bias = (const float*)d_in[4];
  float* out = (float*)d_out;

  const int N = N_NODES_C;
  const int E = N_EDGES_C;
  const int* src = ei;
  const int* dst = ei + E;
  const int NH = NBIN * NCHUNK;        // 50176 hist entries

  char* p = (char*)d_ws;
  auto carve = [&](size_t bytes) {
    void* r = (void*)p;
    p += (bytes + 255) & ~(size_t)255;
    return r;
  };
  __half* h16A     = (__half*)carve((size_t)N * OUT_F * 2);
  __half* h16B     = (__half*)carve((size_t)N * OUT_F * 2);
  int*   row_ptr   = (int*)  carve((size_t)(N + 1) * 4);
  int2*  edges     = (int2*) carve((size_t)E * 8);
  int*   hist      = (int*)  carve((size_t)NH * 4);
  int*   soff      = (int*)  carve((size_t)NH * 4);
  int*   binStart  = (int*)  carve((size_t)(NBIN + 1) * 4);

  // staging in d_out (free scratch until the final hop): sw 12.8MB + d 6.4MB
  int2* stage_sw = (int2*)d_out;
  int*  stage_d  = (int*)((char*)d_out + (size_t)E * 8);

  // 1. h0 = fp16(x @ W^T + b) via MFMA (separate kernel: VGPR headroom)
  gemm_mfma_kernel<<<(N + 255) / 256, 256, 0, stream>>>(x, W, bias, (_Float16*)h16A, N);
  // 2-5. CSR build (no global atomics)
  hist_kernel      <<<NCHUNK, 1024, 0, stream>>>(dst, hist);
  scan_all_kernel  <<<1, 1024, 0, stream>>>(hist, soff, binStart);
  binscatter_kernel<<<NCHUNK, 1024, 0, stream>>>(src, dst, ew, soff, stage_d, stage_sw);
  place_kernel     <<<NBIN, 1024, 0, stream>>>(binStart, stage_d, stage_sw,
                                               row_ptr, edges, N);
  // 6-8. three hops: fp16 -> fp16 -> fp16 -> fp32(out)
  spmm16_kernel<0><<<(N + 31) / 32, 256, 0, stream>>>(row_ptr, edges, h16A, h16B, N);
  spmm16_kernel<0><<<(N + 31) / 32, 256, 0, stream>>>(row_ptr, edges, h16B, h16A, N);
  spmm16_kernel<1><<<(N + 31) / 32, 256, 0, stream>>>(row_ptr, edges, h16A, out, N);
}